// Round 15
// baseline (131.385 us; speedup 1.0000x reference)
//
#include <hip/hip_runtime.h>

// CoPE2d: B=64, NH=16, Wh=Ww=16, N=256, C=64, NPOS=288, BH=1024
// query (BH,256,64) f32; attn_logits (BH,256,256) f32; pos_emb (64,288) f32;
// out (BH,256,256) f32.
// R15: ONE WAVE per 16-row block, one (uncontended) barrier.
// vs R13/R14: table packing via compiler-generated f2bf bit-ops (NOT inline-asm
// cvt_pk reading MFMA results — suspected unhandled MFMA->asm-VALU hazard),
// and simple per-tile B loads (validated R4/R5 pattern).

#define NPOS 288
#define NT   18
#define LTS2 292                   // u16 per table row (584 B stride)

typedef __attribute__((ext_vector_type(8))) short bf16x8;
typedef __attribute__((ext_vector_type(4))) float f32x4;

__device__ __forceinline__ unsigned short f2bf(float f) {   // RNE f32->bf16
    unsigned u = __float_as_uint(f);
    u += 0x7FFF + ((u >> 16) & 1);
    return (unsigned short)(u >> 16);
}
__device__ __forceinline__ unsigned cvt_pk_bf16(float lo, float hi) {
    unsigned r;                       // only applied to plain-loaded values
    asm("v_cvt_pk_bf16_f32 %0, %1, %2" : "=v"(r) : "v"(lo), "v"(hi));
    return r;
}
__device__ __forceinline__ float fast_exp2(float x) {   // v_exp_f32 = 2^x
    float r; asm("v_exp_f32 %0, %1" : "=v"(r) : "v"(x)); return r;
}
__device__ __forceinline__ float fast_fract(float x) {  // x - floor(x)
    float r; asm("v_fract_f32 %0, %1" : "=v"(r) : "v"(x)); return r;
}
__device__ __forceinline__ float bf2f(unsigned short b) {
    return __uint_as_float(((unsigned)b) << 16);
}
__device__ __forceinline__ float sigmoid_f(float x) {   // 1/(1+2^(-x*log2e))
    return __builtin_amdgcn_rcpf(1.0f + fast_exp2(x * -1.44269504088896f));
}

// dst[i] = src[i] + src[i+D] within 16-lane DPP rows, 0 beyond row end.
template <int D>
__device__ __forceinline__ float suffix_step(float v) {
    int s = __builtin_amdgcn_update_dpp(0, __float_as_int(v), 0x100 | D, 0xF, 0xF, true);
    return v + __int_as_float(s);
}
__device__ __forceinline__ float suffix16(float v) {
    return suffix_step<8>(suffix_step<4>(suffix_step<2>(suffix_step<1>(v))));
}

// ---- prep: pos_emb (64x288 f32) -> bf16 B-fragments in ws ------------------
__global__ void prep_kernel(const float* __restrict__ pos_emb,
                            short* __restrict__ wsb) {
    int idx = blockIdx.x * blockDim.x + threadIdx.x;   // 0 .. NT*2*64
    if (idx >= NT * 2 * 64) return;
    int l = idx & 63;
    int s = (idx >> 6) & 1;
    int t = idx >> 7;
    int col = t * 16 + (l & 15);
    int k0  = s * 32 + (l >> 4) * 8;
    short* dst = wsb + idx * 8;
    #pragma unroll
    for (int j = 0; j < 8; ++j)
        dst[j] = (short)f2bf(pos_emb[(k0 + j) * NPOS + col]);
}

__global__ __launch_bounds__(64, 4) void cope2d_kernel(
    const float* __restrict__ query,
    const float* __restrict__ attn_logits,
    const bf16x8* __restrict__ wsb8,
    float* __restrict__ out)
{
    __shared__ unsigned short Lb[16 * LTS2];   // 9344 B, wave-private

    const int lane  = threadIdx.x;             // 0..63
    const int blk   = blockIdx.x;              // 0..16383  (= bh*16 + p)
    const int gbase = blk << 12;               // *4096 elements (16 rows x 256)

    // ---- q loads (A-fragment source: row=lane&15, k=(lane>>4)*8+j) ---------
    const float* qp = query + (blk << 10) + (lane & 15) * 64 + (lane >> 4) * 8;
    f32x4 qa = *(const f32x4*)(qp);
    f32x4 qb = *(const f32x4*)(qp + 4);
    f32x4 qc = *(const f32x4*)(qp + 32);
    f32x4 qd = *(const f32x4*)(qp + 36);

    // ---- gate bases: 4 rows per base, imm = (r&3)*1024 + k*256 B -----------
    const float* gp0 = attn_logits + gbase + lane;    // rows 0..3
    const float* gp1 = gp0 + 4 * 256;                 // rows 4..7
    const float* gp2 = gp0 + 8 * 256;                 // rows 8..11
    const float* gp3 = gp0 + 12 * 256;                // rows 12..15

    // ---- prefetch gate rows 15..12 (ring slots 0..3); hide under GEMM ------
    float gn[4][4];
    #pragma unroll
    for (int k = 0; k < 4; ++k) gn[0][k] = gp3[3 * 256 + k * 64];  // row 15
    #pragma unroll
    for (int k = 0; k < 4; ++k) gn[1][k] = gp3[2 * 256 + k * 64];  // row 14
    #pragma unroll
    for (int k = 0; k < 4; ++k) gn[2][k] = gp3[1 * 256 + k * 64];  // row 13
    #pragma unroll
    for (int k = 0; k < 4; ++k) gn[3][k] = gp3[0 * 256 + k * 64];  // row 12

    // ---- A fragments (cvt_pk on plain-loaded values: validated) ------------
    union { bf16x8 v; unsigned u[4]; } A0, A1;
    A0.u[0] = cvt_pk_bf16(qa[0], qa[1]); A0.u[1] = cvt_pk_bf16(qa[2], qa[3]);
    A0.u[2] = cvt_pk_bf16(qb[0], qb[1]); A0.u[3] = cvt_pk_bf16(qb[2], qb[3]);
    A1.u[0] = cvt_pk_bf16(qc[0], qc[1]); A1.u[1] = cvt_pk_bf16(qc[2], qc[3]);
    A1.u[2] = cvt_pk_bf16(qd[0], qd[1]); A1.u[3] = cvt_pk_bf16(qd[2], qd[3]);

    // ---- full GEMM by this wave: 18 tiles, simple per-tile loop ------------
    // C layout: col = t*16 + (lane&15), rows (lane>>4)*4 + 0..3.
    unsigned short* wp = Lb + (lane >> 4) * 4 * LTS2 + (lane & 15);
    #pragma unroll
    for (int t = 0; t < NT; ++t) {
        bf16x8 b0 = wsb8[(t * 2 + 0) * 64 + lane];
        bf16x8 b1 = wsb8[(t * 2 + 1) * 64 + lane];
        f32x4 c = {0.f, 0.f, 0.f, 0.f};
        c = __builtin_amdgcn_mfma_f32_16x16x32_bf16(A0.v, b0, c, 0, 0, 0);
        c = __builtin_amdgcn_mfma_f32_16x16x32_bf16(A1.v, b1, c, 0, 0, 0);
        const int off = t * 16;                // u16 units
        wp[off]            = f2bf(c[0]);       // compiler-generated VALU:
        wp[off + LTS2]     = f2bf(c[1]);       // MFMA->VALU hazards handled
        wp[off + 2 * LTS2] = f2bf(c[2]);
        wp[off + 3 * LTS2] = f2bf(c[3]);
    }

    __syncthreads();   // cross-lane LDS RAW ordering; uncontended (1 wave)

    // ---- out bases ---------------------------------------------------------
    float* op0 = out + gbase + lane;
    float* op1 = op0 + 4 * 256;
    float* op2 = op0 + 8 * 256;
    float* op3 = op0 + 12 * 256;

    // ---- phase D: rows 15..0, 4 cols/lane (col = k*64 + lane) --------------
    // Scan groups intact: cols 64k+16h..64k+16h+15 live in lanes 16h..16h+15.
    // pos <= 272 < 287: clamp identity; fi+1 <= 273 < 292 in-bounds.
    float acc0 = 0.f, acc1 = 0.f, acc2 = 0.f, acc3 = 0.f;
    #pragma unroll
    for (int r = 15; r >= 0; --r) {
        const int slot = (15 - r) & 3;
        float g0 = sigmoid_f(gn[slot][0]);
        float g1 = sigmoid_f(gn[slot][1]);
        float g2 = sigmoid_f(gn[slot][2]);
        float g3 = sigmoid_f(gn[slot][3]);

        // refill the freed slot with row r-4 (constant-folded base/offsets)
        if (r >= 4) {
            const int rr = r - 4;
            const float* gpb = (rr >= 8) ? gp2 : (rr >= 4) ? gp1 : gp0;
            #pragma unroll
            for (int k = 0; k < 4; ++k)
                gn[slot][k] = gpb[(rr & 3) * 256 + k * 64];
        }

        acc0 += g0; acc1 += g1; acc2 += g2; acc3 += g3;

        float pw0 = suffix16(g0), pw1 = suffix16(g1);
        float pw2 = suffix16(g2), pw3 = suffix16(g3);

        float pos0 = acc0 * 16.0f + pw0;
        float pos1 = acc1 * 16.0f + pw1;
        float pos2 = acc2 * 16.0f + pw2;
        float pos3 = acc3 * 16.0f + pw3;
        int fi0 = (int)pos0, fi1 = (int)pos1, fi2 = (int)pos2, fi3 = (int)pos3;
        float w0 = fast_fract(pos0), w1 = fast_fract(pos1);
        float w2 = fast_fract(pos2), w3 = fast_fract(pos3);

        const unsigned short* Lr = Lb + r * LTS2;   // imm r*584 folds into DS
        float lf0 = bf2f(Lr[fi0]), lc0 = bf2f(Lr[fi0 + 1]);
        float lf1 = bf2f(Lr[fi1]), lc1 = bf2f(Lr[fi1 + 1]);
        float lf2 = bf2f(Lr[fi2]), lc2 = bf2f(Lr[fi2 + 1]);
        float lf3 = bf2f(Lr[fi3]), lc3 = bf2f(Lr[fi3 + 1]);

        float* opb = (r >= 12) ? op3 : (r >= 8) ? op2 : (r >= 4) ? op1 : op0;
        const int ro = (r & 3) * 256;               // imm <= 3072+768 B
        opb[ro]       = lf0 + w0 * (lc0 - lf0);
        opb[ro + 64]  = lf1 + w1 * (lc1 - lf1);
        opb[ro + 128] = lf2 + w2 * (lc2 - lf2);
        opb[ro + 192] = lf3 + w3 * (lc3 - lf3);
    }
}

extern "C" void kernel_launch(void* const* d_in, const int* in_sizes, int n_in,
                              void* d_out, int out_size, void* d_ws, size_t ws_size,
                              hipStream_t stream) {
    const float* query       = (const float*)d_in[0];
    const float* attn_logits = (const float*)d_in[1];
    const float* pos_emb     = (const float*)d_in[2];
    float* outp = (float*)d_out;
    short* wsb  = (short*)d_ws;          // NT*2*64*8 bf16 = 36 KB

    prep_kernel<<<9, 256, 0, stream>>>(pos_emb, wsb);
    cope2d_kernel<<<16384, 64, 0, stream>>>(query, attn_logits,
                                            (const bf16x8*)d_ws, outp);
}

// Round 16
// 119.106 us; speedup vs baseline: 1.1031x; 1.1031x over previous
//
#include <hip/hip_runtime.h>

// CoPE2d: B=64, NH=16, Wh=Ww=16, N=256, C=64, NPOS=288, BH=1024
// query (BH,256,64) f32; attn_logits (BH,256,256) f32; pos_emb (64,288) f32;
// out (BH,256,256) f32.
// R16 = R11 (best: 4-wave block, 4-step pipeline, double-buffered f32 L-table,
// one raw barrier per step) + NON-TEMPORAL output stores: out is write-once/
// never-read; nt keeps it from evicting the re-read inputs out of L3.

#define NPOS 288
#define NT   18          // npos tiles of 16
#define LTSF 292         // f32 Ltab row stride (padded)

typedef __attribute__((ext_vector_type(8))) short bf16x8;
typedef __attribute__((ext_vector_type(4))) float f32x4;

__device__ __forceinline__ unsigned short f2bf(float f) {   // RNE f32->bf16
    unsigned u = __float_as_uint(f);
    u += 0x7FFF + ((u >> 16) & 1);
    return (unsigned short)(u >> 16);
}
// packed f32x2 -> bf16x2 (RNE), single VALU op (plain-loaded inputs only)
__device__ __forceinline__ unsigned cvt_pk_bf16(float lo, float hi) {
    unsigned r;
    asm("v_cvt_pk_bf16_f32 %0, %1, %2" : "=v"(r) : "v"(lo), "v"(hi));
    return r;
}
__device__ __forceinline__ float fast_exp2(float x) {   // v_exp_f32 = 2^x
    float r;
    asm("v_exp_f32 %0, %1" : "=v"(r) : "v"(x));
    return r;
}
__device__ __forceinline__ float fast_fract(float x) {  // x - floor(x)
    float r;
    asm("v_fract_f32 %0, %1" : "=v"(r) : "v"(x));
    return r;
}

// dst[i] = src[i] + src[i+D] within 16-lane DPP rows, 0 beyond row end.
template <int D>
__device__ __forceinline__ float suffix_step(float v) {
    int s = __builtin_amdgcn_update_dpp(0, __float_as_int(v), 0x100 | D, 0xF, 0xF, true);
    return v + __int_as_float(s);
}

// ---- prep: pos_emb (64x288 f32) -> bf16 B-fragments in ws ------------------
__global__ void prep_kernel(const float* __restrict__ pos_emb,
                            short* __restrict__ wsb) {
    int idx = blockIdx.x * blockDim.x + threadIdx.x;   // 0 .. NT*2*64
    if (idx >= NT * 2 * 64) return;
    int l = idx & 63;
    int s = (idx >> 6) & 1;
    int t = idx >> 7;
    int col = t * 16 + (l & 15);
    int k0  = s * 32 + (l >> 4) * 8;
    short* dst = wsb + idx * 8;
    #pragma unroll
    for (int j = 0; j < 8; ++j)
        dst[j] = (short)f2bf(pos_emb[(k0 + j) * NPOS + col]);
}

__global__ __launch_bounds__(256, 4) void cope2d_kernel(
    const float* __restrict__ query,
    const float* __restrict__ attn_logits,
    const bf16x8* __restrict__ wsb8,
    float* __restrict__ out)
{
    __shared__ float Lf[2][16 * LTSF];   // 2 x 18688 B, double-buffered

    const int tid  = threadIdx.x;
    const int lane = tid & 63;
    const int wave = tid >> 6;
    const int blk  = blockIdx.x;               // 0..4095
    const int bh   = blk >> 2;
    const int p0   = (blk & 3) * 4;

    int rowbase = bh * 256 + p0 * 16;          // fits 32-bit
    int gb      = rowbase * 256;               // element idx < 2^26

    // ---- B fragments: load ONCE per block, reused all 4 steps --------------
    bf16x8 Bf[5][2];
    #pragma unroll
    for (int u = 0; u < 5; ++u) {
        int t = wave + 4 * u;
        if (t < NT) {
            Bf[u][0] = wsb8[(t * 2 + 0) * 64 + lane];
            Bf[u][1] = wsb8[(t * 2 + 1) * 64 + lane];
        }
    }

    // ---- prologue: prefetch q + gates for step 0 ---------------------------
    const float* qp = query + rowbase * 64 + (lane & 15) * 64 + (lane >> 4) * 8;
    f32x4 q00 = *(const f32x4*)(qp);
    f32x4 q01 = *(const f32x4*)(qp + 4);
    f32x4 q10 = *(const f32x4*)(qp + 32);
    f32x4 q11 = *(const f32x4*)(qp + 36);
    float gn[16];
    {
        const float* gp = attn_logits + gb + tid;
        #pragma unroll
        for (int i = 0; i < 16; ++i)
            gn[i] = gp[i * 256];               // coalesced
    }

    for (int s = 0; s < 4; ++s) {
        // ---- A fragments via packed cvt (row=lane&15, k=(lane>>4)*8+j) -----
        union { bf16x8 v; unsigned u[4]; } A0, A1;
        A0.u[0] = cvt_pk_bf16(q00[0], q00[1]);
        A0.u[1] = cvt_pk_bf16(q00[2], q00[3]);
        A0.u[2] = cvt_pk_bf16(q01[0], q01[1]);
        A0.u[3] = cvt_pk_bf16(q01[2], q01[3]);
        A1.u[0] = cvt_pk_bf16(q10[0], q10[1]);
        A1.u[1] = cvt_pk_bf16(q10[2], q10[3]);
        A1.u[2] = cvt_pk_bf16(q11[0], q11[1]);
        A1.u[3] = cvt_pk_bf16(q11[2], q11[3]);

        // ---- MFMA GEMM -> Lf[s&1] (f32) ------------------------------------
        float* Lfs = Lf[s & 1];
        #pragma unroll
        for (int u = 0; u < 5; ++u) {
            int t = wave + 4 * u;
            if (t < NT) {
                f32x4 c = {0.f, 0.f, 0.f, 0.f};
                c = __builtin_amdgcn_mfma_f32_16x16x32_bf16(A0.v, Bf[u][0], c, 0, 0, 0);
                c = __builtin_amdgcn_mfma_f32_16x16x32_bf16(A1.v, Bf[u][1], c, 0, 0, 0);
                const int col = t * 16 + (lane & 15);
                const int r0  = (lane >> 4) * 4;
                #pragma unroll
                for (int r = 0; r < 4; ++r)
                    Lfs[(r0 + r) * LTSF + col] = c[r];
            }
        }

        // ---- sigmoid of current gates: 1/(1 + 2^(-x*log2e)) ----------------
        float g[16];
        #pragma unroll
        for (int i = 0; i < 16; ++i) {
            float e = fast_exp2(gn[i] * -1.44269504088896f);
            g[i] = __builtin_amdgcn_rcpf(1.0f + e);
        }

        const int gout = gb;       // store base for this step

        // ---- RAW barrier: drain LDS writes only; stores/prefetch untouched -
        asm volatile("s_waitcnt lgkmcnt(0)" ::: "memory");
        __builtin_amdgcn_s_barrier();

        // ---- prefetch step s+1 (in flight under phase D + next GEMM) -------
        if (s < 3) {
            rowbase += 16;
            gb += 16 * 256;
            const float* qp2 = query + rowbase * 64 + (lane & 15) * 64 + (lane >> 4) * 8;
            q00 = *(const f32x4*)(qp2);
            q01 = *(const f32x4*)(qp2 + 4);
            q10 = *(const f32x4*)(qp2 + 32);
            q11 = *(const f32x4*)(qp2 + 36);
            const float* gp2 = attn_logits + gb + tid;
            #pragma unroll
            for (int i = 0; i < 16; ++i)
                gn[i] = gp2[i * 256];
        }

        // ---- phase D: pos_h/pos_w -> gather+lerp -> nt-store ---------------
        // pos = sfx*16 + pw <= 272 < 287: clamp identity; fi+1 <= 273 < 292.
        float* op = out + gout + tid;
        float run = 0.f;
        #pragma unroll
        for (int half = 1; half >= 0; --half) {
            const int i0 = half * 8;
            float r8[8];
            #pragma unroll
            for (int k = 7; k >= 0; --k) { run += g[i0 + k]; r8[k] = run; }

            float w8[8]; int fi8[8];
            #pragma unroll
            for (int k = 0; k < 8; ++k) {
                float pw = suffix_step<8>(suffix_step<4>(suffix_step<2>(suffix_step<1>(g[i0 + k]))));
                float pos = r8[k] * 16.0f + pw;
                fi8[k] = (int)pos;              // trunc == floor (pos >= 0)
                w8[k]  = fast_fract(pos);       // pos - floor(pos)
            }
            float lf8[8], lc8[8];
            #pragma unroll
            for (int k = 0; k < 8; ++k) {
                const float* Lr = Lfs + (i0 + k) * LTSF;
                lf8[k] = Lr[fi8[k]];
                lc8[k] = Lr[fi8[k] + 1];
            }
            #pragma unroll
            for (int k = 0; k < 8; ++k)
                __builtin_nontemporal_store(
                    lf8[k] + w8[k] * (lc8[k] - lf8[k]),
                    op + (i0 + k) * 256);       // nt: don't evict inputs from L2/L3
        }
        // cross-wave WAR on Lf[s&1] covered by the raw barriers of steps
        // s+1, s+2 (double buffer); ds_read results consumed above.
    }
}

extern "C" void kernel_launch(void* const* d_in, const int* in_sizes, int n_in,
                              void* d_out, int out_size, void* d_ws, size_t ws_size,
                              hipStream_t stream) {
    const float* query       = (const float*)d_in[0];
    const float* attn_logits = (const float*)d_in[1];
    const float* pos_emb     = (const float*)d_in[2];
    float* outp = (float*)d_out;
    short* wsb  = (short*)d_ws;          // NT*2*64*8 bf16 = 36 KB

    prep_kernel<<<9, 256, 0, stream>>>(pos_emb, wsb);
    cope2d_kernel<<<4096, 256, 0, stream>>>(query, attn_logits,
                                            (const bf16x8*)d_ws, outp);
}

// Round 17
// 119.012 us; speedup vs baseline: 1.1040x; 1.0008x over previous
//
#include <hip/hip_runtime.h>

// CoPE2d: B=64, NH=16, Wh=Ww=16, N=256, C=64, NPOS=288, BH=1024
// R17 = R16 (4-wave / 4-step pipeline, dbuf f32 L-table, raw barrier, nt
// stores) + float4 phase-D layout: lane owns cols 4l..4l+3, wave w owns rows
// 4w..4w+3. Loads/stores dwordx4 (4x fewer VMEM), scan = 3 local adds +
// 3 masked DPP (5x fewer DPP). pos_h crosses waves via 4KB dbuf block-sum
// exchange in LDS (folded into the existing barrier).

#define NPOS 288
#define NT   18
#define LTSF 292         // f32 Ltab row stride (padded)

typedef __attribute__((ext_vector_type(8))) short bf16x8;
typedef __attribute__((ext_vector_type(4))) float f32x4;

__device__ __forceinline__ unsigned short f2bf(float f) {
    unsigned u = __float_as_uint(f);
    u += 0x7FFF + ((u >> 16) & 1);
    return (unsigned short)(u >> 16);
}
__device__ __forceinline__ unsigned cvt_pk_bf16(float lo, float hi) {
    unsigned r;                       // plain-loaded inputs only (R13 lesson)
    asm("v_cvt_pk_bf16_f32 %0, %1, %2" : "=v"(r) : "v"(lo), "v"(hi));
    return r;
}
__device__ __forceinline__ float fast_exp2(float x) {
    float r; asm("v_exp_f32 %0, %1" : "=v"(r) : "v"(x)); return r;
}
__device__ __forceinline__ float fast_fract(float x) {
    float r; asm("v_fract_f32 %0, %1" : "=v"(r) : "v"(x)); return r;
}
__device__ __forceinline__ float sigmoid_f(float x) {
    return __builtin_amdgcn_rcpf(1.0f + fast_exp2(x * -1.44269504088896f));
}
// row_shl:D within 16-lane DPP rows, 0 beyond row end.
template <int D>
__device__ __forceinline__ float row_shl(float v) {
    int s = __builtin_amdgcn_update_dpp(0, __float_as_int(v), 0x100 | D, 0xF, 0xF, true);
    return __int_as_float(s);
}

// ---- prep: pos_emb (64x288 f32) -> bf16 B-fragments in ws ------------------
__global__ void prep_kernel(const float* __restrict__ pos_emb,
                            short* __restrict__ wsb) {
    int idx = blockIdx.x * blockDim.x + threadIdx.x;
    if (idx >= NT * 2 * 64) return;
    int l = idx & 63;
    int s = (idx >> 6) & 1;
    int t = idx >> 7;
    int col = t * 16 + (l & 15);
    int k0  = s * 32 + (l >> 4) * 8;
    short* dst = wsb + idx * 8;
    #pragma unroll
    for (int j = 0; j < 8; ++j)
        dst[j] = (short)f2bf(pos_emb[(k0 + j) * NPOS + col]);
}

__global__ __launch_bounds__(256, 3) void cope2d_kernel(
    const float* __restrict__ query,
    const float* __restrict__ attn_logits,
    const bf16x8* __restrict__ wsb8,
    float* __restrict__ out)
{
    __shared__ float Lf[2][16 * LTSF];   // 2 x 18688 B L-table
    __shared__ float Bs[2][4 * 256];     // 2 x 4096 B per-col wave block-sums

    const int tid  = threadIdx.x;
    const int lane = tid & 63;
    const int wave = tid >> 6;
    const int blk  = blockIdx.x;               // 0..4095
    const int bh   = blk >> 2;
    const int p0   = (blk & 3) * 4;

    int rowbase = bh * 256 + p0 * 16;
    int gb      = rowbase * 256;

    // scan group masks: contribution from lane l+k valid iff (l&3)+k <= 3
    const int l3 = lane & 3;
    const float m1 = (l3 < 3) ? 1.0f : 0.0f;
    const float m2 = (l3 < 2) ? 1.0f : 0.0f;
    const float m3 = (l3 < 1) ? 1.0f : 0.0f;

    // ---- B fragments: load ONCE, reused all 4 steps ------------------------
    bf16x8 Bf[5][2];
    #pragma unroll
    for (int u = 0; u < 5; ++u) {
        int t = wave + 4 * u;
        if (t < NT) {
            Bf[u][0] = wsb8[(t * 2 + 0) * 64 + lane];
            Bf[u][1] = wsb8[(t * 2 + 1) * 64 + lane];
        }
    }

    // ---- prologue: prefetch q + gates (4 dwordx4: rows 4w..4w+3, cols 4l..)-
    const float* qp = query + rowbase * 64 + (lane & 15) * 64 + (lane >> 4) * 8;
    f32x4 q00 = *(const f32x4*)(qp);
    f32x4 q01 = *(const f32x4*)(qp + 4);
    f32x4 q10 = *(const f32x4*)(qp + 32);
    f32x4 q11 = *(const f32x4*)(qp + 36);
    f32x4 gnv[4];
    {
        const float* gp = attn_logits + gb + wave * 4 * 256 + lane * 4;
        #pragma unroll
        for (int j = 0; j < 4; ++j)
            gnv[j] = *(const f32x4*)(gp + j * 256);
    }

    for (int s = 0; s < 4; ++s) {
        // ---- A fragments ----------------------------------------------------
        union { bf16x8 v; unsigned u[4]; } A0, A1;
        A0.u[0] = cvt_pk_bf16(q00[0], q00[1]);
        A0.u[1] = cvt_pk_bf16(q00[2], q00[3]);
        A0.u[2] = cvt_pk_bf16(q01[0], q01[1]);
        A0.u[3] = cvt_pk_bf16(q01[2], q01[3]);
        A1.u[0] = cvt_pk_bf16(q10[0], q10[1]);
        A1.u[1] = cvt_pk_bf16(q10[2], q10[3]);
        A1.u[2] = cvt_pk_bf16(q11[0], q11[1]);
        A1.u[3] = cvt_pk_bf16(q11[2], q11[3]);

        // ---- MFMA GEMM -> Lf[s&1] ------------------------------------------
        float* Lfs = Lf[s & 1];
        #pragma unroll
        for (int u = 0; u < 5; ++u) {
            int t = wave + 4 * u;
            if (t < NT) {
                f32x4 c = {0.f, 0.f, 0.f, 0.f};
                c = __builtin_amdgcn_mfma_f32_16x16x32_bf16(A0.v, Bf[u][0], c, 0, 0, 0);
                c = __builtin_amdgcn_mfma_f32_16x16x32_bf16(A1.v, Bf[u][1], c, 0, 0, 0);
                const int col = t * 16 + (lane & 15);
                const int r0  = (lane >> 4) * 4;
                #pragma unroll
                for (int r = 0; r < 4; ++r)
                    Lfs[(r0 + r) * LTSF + col] = c[r];
            }
        }

        // ---- sigmoid (own 4 rows x 4 cols) + block-sum to LDS --------------
        f32x4 gs[4];
        #pragma unroll
        for (int j = 0; j < 4; ++j)
            #pragma unroll
            for (int c4 = 0; c4 < 4; ++c4)
                gs[j][c4] = sigmoid_f(gnv[j][c4]);
        {
            f32x4 bsv = gs[0] + gs[1] + gs[2] + gs[3];
            *(f32x4*)&Bs[s & 1][wave * 256 + lane * 4] = bsv;
        }

        const int gout = gb;

        // ---- raw barrier: drains LDS writes (table + block-sums) only ------
        asm volatile("s_waitcnt lgkmcnt(0)" ::: "memory");
        __builtin_amdgcn_s_barrier();

        // ---- SA = sum of later waves' block-sums (pos_h prefix from below) -
        f32x4 SA = {0.f, 0.f, 0.f, 0.f};
        for (int w2 = wave + 1; w2 < 4; ++w2)
            SA += *(const f32x4*)&Bs[s & 1][w2 * 256 + lane * 4];

        // ---- prefetch step s+1 ---------------------------------------------
        if (s < 3) {
            rowbase += 16;
            gb += 16 * 256;
            const float* qp2 = query + rowbase * 64 + (lane & 15) * 64 + (lane >> 4) * 8;
            q00 = *(const f32x4*)(qp2);
            q01 = *(const f32x4*)(qp2 + 4);
            q10 = *(const f32x4*)(qp2 + 32);
            q11 = *(const f32x4*)(qp2 + 36);
            const float* gp2 = attn_logits + gb + wave * 4 * 256 + lane * 4;
            #pragma unroll
            for (int j = 0; j < 4; ++j)
                gnv[j] = *(const f32x4*)(gp2 + j * 256);
        }

        // ---- phase D: own rows 4w+3..4w+0, 4 consecutive cols/lane ---------
        // pos <= 272 < 287: clamp identity; fi+1 <= 273 < 292 in-bounds.
        float a0 = SA[0], a1 = SA[1], a2 = SA[2], a3 = SA[3];
        float* op = out + gout + (wave * 4) * 256 + lane * 4;
        #pragma unroll
        for (int j = 3; j >= 0; --j) {
            float g0 = gs[j][0], g1 = gs[j][1], g2 = gs[j][2], g3 = gs[j][3];
            // local col suffix within lane
            float s3 = g3, s2 = g2 + g3, s1 = g1 + s2, s0 = g0 + s1;
            // cross-lane remainder within 4-lane group (masked row_shl)
            float R = fmaf(m1, row_shl<1>(s0),
                      fmaf(m2, row_shl<2>(s0), m3 * row_shl<3>(s0)));
            // pos_h accumulators (inclusive, rows below already in SA)
            a0 += g0; a1 += g1; a2 += g2; a3 += g3;

            float pos0 = fmaf(a0, 16.0f, s0 + R);
            float pos1 = fmaf(a1, 16.0f, s1 + R);
            float pos2 = fmaf(a2, 16.0f, s2 + R);
            float pos3 = fmaf(a3, 16.0f, s3 + R);
            int  fi0 = (int)pos0, fi1 = (int)pos1, fi2 = (int)pos2, fi3 = (int)pos3;
            float w0 = fast_fract(pos0), w1 = fast_fract(pos1);
            float w2 = fast_fract(pos2), w3 = fast_fract(pos3);

            const float* Lr = Lfs + (wave * 4 + j) * LTSF;
            float lf0 = Lr[fi0], lc0 = Lr[fi0 + 1];
            float lf1 = Lr[fi1], lc1 = Lr[fi1 + 1];
            float lf2 = Lr[fi2], lc2 = Lr[fi2 + 1];
            float lf3 = Lr[fi3], lc3 = Lr[fi3 + 1];

            f32x4 o;
            o[0] = lf0 + w0 * (lc0 - lf0);
            o[1] = lf1 + w1 * (lc1 - lf1);
            o[2] = lf2 + w2 * (lc2 - lf2);
            o[3] = lf3 + w3 * (lc3 - lf3);
            __builtin_nontemporal_store(o, (f32x4*)(op + j * 256));
        }
        // WAR on Lf[s&1]/Bs[s&1] covered by the raw barriers of steps s+1,s+2.
    }
}

extern "C" void kernel_launch(void* const* d_in, const int* in_sizes, int n_in,
                              void* d_out, int out_size, void* d_ws, size_t ws_size,
                              hipStream_t stream) {
    const float* query       = (const float*)d_in[0];
    const float* attn_logits = (const float*)d_in[1];
    const float* pos_emb     = (const float*)d_in[2];
    float* outp = (float*)d_out;
    short* wsb  = (short*)d_ws;          // NT*2*64*8 bf16 = 36 KB

    prep_kernel<<<9, 256, 0, stream>>>(pos_emb, wsb);
    cope2d_kernel<<<4096, 256, 0, stream>>>(query, attn_logits,
                                            (const bf16x8*)d_ws, outp);
}